// Round 5
// baseline (935.869 us; speedup 1.0000x reference)
//
#include <hip/hip_runtime.h>
#include <hip/hip_fp16.h>
#include <stdint.h>

typedef _Float16 f16;
typedef _Float16 f16x8 __attribute__((ext_vector_type(8)));
typedef float f32x4 __attribute__((ext_vector_type(4)));

#define NROWS 262144
#define MROWS 32            // rows per group (2 x N=16 column blocks)
#define TPB   512           // 8 waves
#define GPB   4             // row-groups per block
#define NBLK  (NROWS / (MROWS * GPB))   // 2048
#define K     192           // padded vocab
#define THR   0.9921875f

// workspace byte offsets (all f16)
#define WS_TABT 0                        // [768][192]
#define WS_W2FS (768 * 192 * 2)          // [16][768]
#define WS_W2VA (WS_W2FS + 16 * 768 * 2) // [16][640]

// LDS layout (1 block/CU):
//  cntfx  int  [4][32][192]   @0       (98304)  -- scatter grid (phase A)
//  fsfeat f16  [32][776]      @0       (49664)  -- feature space (reuses grid)
//  vafeat f16  [32][648]      @49664   (41472, ends 91136)
//  cnt16  f16  [4][32][200]   @98304   (51200, ends 149504) -- packed counts
//  facc/vacc f32 [512]+[512]  @149504  (4096, ends 153600)
#define FS_STRIDE 776
#define VA_STRIDE 648
#define VA_BASE   49664
#define CNT_BASE  98304
#define ACC_BASE  149504
#define SMEM_SZ   153600

__device__ __forceinline__ f16x8 bc8(uint4 u) {
  union { uint4 u; f16x8 h; } x; x.u = u; return x.h;
}
__device__ __forceinline__ float clampv(float x) {
  return fminf(fmaxf(x, -THR), THR);
}
__device__ __forceinline__ uint32_t packh2(float a, float b) {
  union { __half2 h; uint32_t u; } cv; cv.h = __floats2half2_rn(a, b); return cv.u;
}
__device__ __forceinline__ f32x4 chain6(const uint4* af, const uint4* bf) {
  f32x4 a = {0.f, 0.f, 0.f, 0.f};
  #pragma unroll
  for (int ks = 0; ks < 6; ++ks)
    a = __builtin_amdgcn_mfma_f32_16x16x32_f16(bc8(af[ks]), bc8(bf[ks]), a, 0, 0, 0);
  return a;
}

// ---------------- prepack ----------------------------------------------------
__global__ void prepack(const float* __restrict__ emb_fs, const float* __restrict__ emb_va,
                        const float* __restrict__ emb_ha, const float* __restrict__ emb_ra,
                        const float* __restrict__ fs_w,   const float* __restrict__ absva_w,
                        const float* __restrict__ absha_w,const float* __restrict__ absra_w,
                        const float* __restrict__ va_w,   const float* __restrict__ fsxva_w,
                        const float* __restrict__ haxra_w, f16* __restrict__ ws) {
  if (blockIdx.x < 24) {
    __shared__ float tile[192 * 33];
    int u0 = blockIdx.x * 32;
    int t = threadIdx.x;
    #pragma unroll 4
    for (int i = 0; i < 24; ++i) {
      int idx = t + 256 * i;            // 6144 = 192k x 32u
      int k = idx >> 5;
      int c = idx & 31;
      int u = u0 + c;
      float v = 0.f;
      if (k < 185) {
        if      (u < 256) v = emb_fs[k * 256 + u];
        else if (u < 512) v = emb_va[k * 256 + (u - 256)];
        else if (u < 640) v = emb_ha[k * 128 + (u - 512)];
        else              v = emb_ra[k * 128 + (u - 640)];
      }
      tile[k * 33 + c] = v;
    }
    __syncthreads();
    #pragma unroll 4
    for (int i = 0; i < 24; ++i) {
      int idx = t + 256 * i;
      int u = idx / 192;
      int k = idx % 192;
      ws[(u0 + u) * 192 + k] = (f16)tile[k * 33 + u];
    }
  } else {
    int gid = (blockIdx.x - 24) * 256 + threadIdx.x;
    if (gid < 16 * 768) {                        // w2fs[j][k]
      int j = gid / 768, k = gid % 768;
      float v = (k < 256) ? fs_w[j * 256 + k]
              : (k < 512) ? absva_w[j * 256 + (k - 256)]
              : (k < 640) ? absha_w[j * 128 + (k - 512)]
                          : absra_w[j * 128 + (k - 640)];
      ((f16*)((char*)ws + WS_W2FS))[j * 768 + k] = (f16)v;
    } else if (gid < 16 * 768 + 16 * 640) {      // w2va[j][k]
      int g = gid - 16 * 768;
      int j = g / 640, k = g % 640;
      float v = (k < 256) ? va_w[j * 256 + k]
              : (k < 512) ? fsxva_w[j * 256 + (k - 256)]
                          : haxra_w[j * 128 + (k - 512)];
      ((f16*)((char*)ws + WS_W2VA))[j * 640 + k] = (f16)v;
    }
  }
}

// ---------------- main fused kernel ------------------------------------------
// 2 waves/EU (8 waves/CU, 1 block/CU): full register budget for resident A.
__global__ __launch_bounds__(TPB, 2)
void rengar_main(const int* __restrict__ pst_idx, const float* __restrict__ color_sign,
                 const float* __restrict__ sob_sign, const float* __restrict__ wtm,
                 const float* __restrict__ tempo_w, const float* __restrict__ fs_b,
                 const float* __restrict__ out_va_w, const float* __restrict__ out_fsxva_w,
                 const f16* __restrict__ ws, float* __restrict__ out) {
  __shared__ __align__(16) char smem[SMEM_SZ];

  const int tid  = threadIdx.x;
  const int lane = tid & 63;
  const int w    = tid >> 6;          // wave 0..7
  const int l15  = lane & 15;
  const int q    = lane >> 4;

  const f16* tabT = (const f16*)((const char*)ws + WS_TABT);
  uint32_t* cnt16 = (uint32_t*)(smem + CNT_BASE);
  float* facc = (float*)(smem + ACC_BASE);
  float* vacc = facc + 512;

  // ---- hoist layer-1 A fragments: wave-local pairing
  //      tiles: fs(32w), fs(32w+16), va(32w), va(32w+16), ha(16w), ra(16w)
  uint4 afr1[36];
  {
    const int bases[6] = { 32 * w, 32 * w + 16, 256 + 32 * w, 272 + 32 * w,
                           512 + 16 * w, 640 + 16 * w };
    #pragma unroll
    for (int i = 0; i < 6; ++i) {
      const f16* ap = tabT + (bases[i] + l15) * K + q * 8;
      #pragma unroll
      for (int ks = 0; ks < 6; ++ks) afr1[i * 6 + ks] = *(const uint4*)(ap + ks * 32);
    }
  }

  // ---- hoist layer-2 A fragments (split-K: fs -> waves 0-3, va -> waves 4-7)
  uint4 a2[6];
  if (w < 4) {
    const f16* A = (const f16*)((const char*)ws + WS_W2FS) + l15 * 768 + w * 192 + q * 8;
    #pragma unroll
    for (int ks = 0; ks < 6; ++ks) a2[ks] = *(const uint4*)(A + ks * 32);
  } else {
    const f16* A = (const f16*)((const char*)ws + WS_W2VA) + l15 * 640 + (w - 4) * 160 + q * 8;
    #pragma unroll
    for (int ks = 0; ks < 5; ++ks) a2[ks] = *(const uint4*)(A + ks * 32);
  }

  const int jj = tid & 15;
  const float bj  = fs_b[jj];
  const float w1j = out_va_w[jj];
  const float w2j = out_fsxva_w[jj];

  // ---- prefetch group-0 inputs (2 entries/thread: rows 0-15 and 16-31) ----
  const int ebase = blockIdx.x * GPB * MROWS * 32;   // 4096 entries/block
  int   vidx0 = pst_idx[ebase + tid];
  int   vidx1 = pst_idx[ebase + 512 + tid];
  float cc0   = color_sign[ebase + tid];
  float cc1   = color_sign[ebase + 512 + tid];
  float ss0   = sob_sign[ebase + tid];
  float ss1   = sob_sign[ebase + 512 + tid];
  float wtr0  = wtm[blockIdx.x * GPB * MROWS + l15];
  float wtr1  = wtm[blockIdx.x * GPB * MROWS + 16 + l15];

  // ---- prologue: zero count grid + accumulators ----
  {
    int4 z = make_int4(0, 0, 0, 0);
    int4* p = (int4*)smem;
    #pragma unroll
    for (int i = 0; i < 12; ++i) p[tid + 512 * i] = z;          // grid 0..98304
    if (tid < 256) ((int4*)(smem + ACC_BASE))[tid] = z;         // facc/vacc
  }
  __syncthreads();

  #pragma unroll 1
  for (int g = 0; g < GPB; ++g) {
    const int r0 = (blockIdx.x * GPB + g) * MROWS;

    // ---- P2: scatter (LDS int atomics, scale 2^16) -- grid pre-zeroed
    {
      int* gp = (int*)smem;
      const int row0 = tid >> 5;                 // 0..15
      int* p0 = gp + row0 * K + vidx0;
      atomicAdd(p0,          65536);
      atomicAdd(p0 +  6144, __float2int_rn(cc0 * 65536.f));
      atomicAdd(p0 + 12288, __float2int_rn(ss0 * 65536.f));
      atomicAdd(p0 + 18432, __float2int_rn(cc0 * ss0 * 65536.f));
      int* p1 = gp + (16 + row0) * K + vidx1;
      atomicAdd(p1,          65536);
      atomicAdd(p1 +  6144, __float2int_rn(cc1 * 65536.f));
      atomicAdd(p1 + 12288, __float2int_rn(ss1 * 65536.f));
      atomicAdd(p1 + 18432, __float2int_rn(cc1 * ss1 * 65536.f));
    }
    // prefetch next group's inputs
    float nwt0 = wtr0, nwt1 = wtr1;
    if (g + 1 < GPB) {
      int nb = ebase + (g + 1) * 1024;
      vidx0 = pst_idx[nb + tid];        vidx1 = pst_idx[nb + 512 + tid];
      cc0   = color_sign[nb + tid];     cc1   = color_sign[nb + 512 + tid];
      ss0   = sob_sign[nb + tid];       ss1   = sob_sign[nb + 512 + tid];
      nwt0  = wtm[r0 + MROWS + l15];    nwt1  = wtm[r0 + MROWS + 16 + l15];
    }
    __syncthreads();                                       // (1)

    // ---- P3: one-pass convert int grid -> cnt16 (disjoint region, no WAR)
    {
      const float inv = 1.f / 65536.f;
      const int4* src = (const int4*)smem;
      #pragma unroll
      for (int i = 0; i < 12; ++i) {
        int idx = tid + 512 * i;            // int4 index (lane-consecutive reads)
        int4 t4 = src[idx];
        int tb  = idx / 1536;
        int rem = idx - tb * 1536;
        int row = rem / 48;
        int k4  = rem - row * 48;
        uint2 o;
        o.x = packh2((float)t4.x * inv, (float)t4.y * inv);
        o.y = packh2((float)t4.z * inv, (float)t4.w * inv);
        *(uint2*)(cnt16 + tb * 3200 + row * 100 + k4 * 2) = o;  // lane-consecutive
      }
    }
    __syncthreads();                                       // (2)

    // ---- P4: layer-1 GEMM + clamp + ALL derived features in registers,
    //      conflict-free uint2 stores. A-fragments reused across 2 N-blocks.
    {
      uint4 bA[6], bB[6];
      #pragma unroll
      for (int n = 0; n < 2; ++n) {
        const uint32_t* bpA = cnt16 + (n * 16 + l15) * 100 + q * 4;   // fs counts
        const uint32_t* bpB = bpA + 3200;                             // va counts
        #pragma unroll
        for (int ks = 0; ks < 6; ++ks) {
          bA[ks] = *(const uint4*)(bpA + ks * 16);
          bB[ks] = *(const uint4*)(bpB + ks * 16);
        }
        const float wtrn = n ? wtr1 : wtr0;
        char* fsrow = smem + (n * 16 + l15) * (FS_STRIDE * 2);
        char* varow = smem + VA_BASE + (n * 16 + l15) * (VA_STRIDE * 2);
        #pragma unroll
        for (int half = 0; half < 2; ++half) {
          f32x4 fA = chain6(&afr1[half * 6], bA);        // fs1 tile
          f32x4 vA = chain6(&afr1[(2 + half) * 6], bB);  // va1 tile (same u range)
          const int m0 = 32 * w + 16 * half + q * 4;
          float4 tw = *(const float4*)(tempo_w + m0);
          float a0 = clampv(fA[0]), a1 = clampv(fA[1]);
          float a2c = clampv(fA[2]), a3 = clampv(fA[3]);
          float b0 = clampv(vA[0] + wtrn * tw.x);
          float b1 = clampv(vA[1] + wtrn * tw.y);
          float b2 = clampv(vA[2] + wtrn * tw.z);
          float b3 = clampv(vA[3] + wtrn * tw.w);
          uint2 o;
          o.x = packh2(a0, a1); o.y = packh2(a2c, a3);
          *(uint2*)(fsrow + m0 * 2) = o;                               // fs1
          o.x = packh2(fabsf(b0), fabsf(b1)); o.y = packh2(fabsf(b2), fabsf(b3));
          *(uint2*)(fsrow + (256 + m0) * 2) = o;                       // |va1|
          o.x = packh2(b0, b1); o.y = packh2(b2, b3);
          *(uint2*)(varow + m0 * 2) = o;                               // va1
          o.x = packh2(a0 * b0, a1 * b1); o.y = packh2(a2c * b2, a3 * b3);
          *(uint2*)(varow + (256 + m0) * 2) = o;                       // fs1*va1
        }
      }
      #pragma unroll
      for (int n = 0; n < 2; ++n) {
        const uint32_t* bpH = cnt16 + 2 * 3200 + (n * 16 + l15) * 100 + q * 4;
        const uint32_t* bpR = bpH + 3200;
        #pragma unroll
        for (int ks = 0; ks < 6; ++ks) {
          bA[ks] = *(const uint4*)(bpH + ks * 16);
          bB[ks] = *(const uint4*)(bpR + ks * 16);
        }
        f32x4 hA = chain6(&afr1[24], bA);                // ha1 tile
        f32x4 rA = chain6(&afr1[30], bB);                // ra1 tile (same s range)
        const int s0 = 16 * w + q * 4;
        char* fsrow = smem + (n * 16 + l15) * (FS_STRIDE * 2);
        char* varow = smem + VA_BASE + (n * 16 + l15) * (VA_STRIDE * 2);
        float h0 = clampv(hA[0]), h1 = clampv(hA[1]);
        float h2 = clampv(hA[2]), h3 = clampv(hA[3]);
        float r0c = clampv(rA[0]), r1 = clampv(rA[1]);
        float r2 = clampv(rA[2]), r3 = clampv(rA[3]);
        uint2 o;
        o.x = packh2(fabsf(h0), fabsf(h1)); o.y = packh2(fabsf(h2), fabsf(h3));
        *(uint2*)(fsrow + (512 + s0) * 2) = o;                         // |ha1|
        o.x = packh2(fabsf(r0c), fabsf(r1)); o.y = packh2(fabsf(r2), fabsf(r3));
        *(uint2*)(fsrow + (640 + s0) * 2) = o;                         // |ra1|
        o.x = packh2(h0 * r0c, h1 * r1); o.y = packh2(h2 * r2, h3 * r3);
        *(uint2*)(varow + (512 + s0) * 2) = o;                         // ha1*ra1
      }
    }
    __syncthreads();                                       // (3)

    // ---- P7: layer-2 split-K, both N-blocks, combine via LDS f32 atomics
    {
      #pragma unroll
      for (int n = 0; n < 2; ++n) {
        f32x4 acc2 = {0.f, 0.f, 0.f, 0.f};
        const char* frow = smem + (n * 16 + l15) * (FS_STRIDE * 2);
        const char* vrow = smem + VA_BASE + (n * 16 + l15) * (VA_STRIDE * 2);
        if (w < 4) {
          #pragma unroll
          for (int ks = 0; ks < 6; ++ks) {
            uint4 bf = *(const uint4*)(frow + (w * 192 + ks * 32 + q * 8) * 2);
            acc2 = __builtin_amdgcn_mfma_f32_16x16x32_f16(bc8(a2[ks]), bc8(bf), acc2, 0, 0, 0);
          }
        } else {
          #pragma unroll
          for (int ks = 0; ks < 5; ++ks) {
            uint4 bf = *(const uint4*)(vrow + ((w - 4) * 160 + ks * 32 + q * 8) * 2);
            acc2 = __builtin_amdgcn_mfma_f32_16x16x32_f16(bc8(a2[ks]), bc8(bf), acc2, 0, 0, 0);
          }
        }
        float* dstacc = (w < 4) ? facc : vacc;
        int base = (n * 16 + l15) << 4;
        #pragma unroll
        for (int r = 0; r < 4; ++r) {
          int j = q * 4 + r;
          atomicAdd(&dstacc[base + ((j + l15) & 15)], acc2[r]);
        }
      }
    }
    __syncthreads();                                       // (4)

    // ---- P8: all 512 threads: read accum (+re-zero), bias/clamp, shfl
    //      reduce, output; then re-zero the count grid for the next group.
    {
      int b = tid >> 4;                  // batch row 0..31
      int idx = (b << 4) | ((jj + b) & 15);
      float f = facc[idx];
      float v = vacc[idx];
      facc[idx] = 0.f;
      vacc[idx] = 0.f;
      f = clampv(f + bj);
      v = clampv(v);
      float rr = v * w1j + f * v * w2j;
      rr += __shfl_xor(rr, 1);
      rr += __shfl_xor(rr, 2);
      rr += __shfl_xor(rr, 4);
      rr += __shfl_xor(rr, 8);
      if (jj == 0) out[r0 + b] = rr;
      if (g + 1 < GPB) {
        int4 z = make_int4(0, 0, 0, 0);
        int4* p = (int4*)smem;
        #pragma unroll
        for (int i = 0; i < 12; ++i) p[tid + 512 * i] = z;   // grid 0..98304
      }
    }
    __syncthreads();                                       // (5)
    wtr0 = nwt0; wtr1 = nwt1;
  }
}

extern "C" void kernel_launch(void* const* d_in, const int* in_sizes, int n_in,
                              void* d_out, int out_size, void* d_ws, size_t ws_size,
                              hipStream_t stream) {
  const int*   pst_idx     = (const int*)  d_in[0];
  const float* color_sign  = (const float*)d_in[1];
  const float* sob_sign    = (const float*)d_in[2];
  const float* wtm         = (const float*)d_in[3];
  const float* emb_fs      = (const float*)d_in[4];
  const float* emb_va      = (const float*)d_in[5];
  const float* emb_ha      = (const float*)d_in[6];
  const float* emb_ra      = (const float*)d_in[7];
  const float* tempo_w     = (const float*)d_in[8];
  const float* fs_b        = (const float*)d_in[10];
  const float* fs_w        = (const float*)d_in[9];
  const float* absva_w     = (const float*)d_in[11];
  const float* absha_w     = (const float*)d_in[12];
  const float* absra_w     = (const float*)d_in[13];
  const float* va_w        = (const float*)d_in[14];
  const float* fsxva_w     = (const float*)d_in[15];
  const float* haxra_w     = (const float*)d_in[16];
  const float* out_va_w    = (const float*)d_in[17];
  const float* out_fsxva_w = (const float*)d_in[18];
  float* out = (float*)d_out;
  f16* ws = (f16*)d_ws;

  prepack<<<24 + 88, 256, 0, stream>>>(emb_fs, emb_va, emb_ha, emb_ra,
                                       fs_w, absva_w, absha_w, absra_w,
                                       va_w, fsxva_w, haxra_w, ws);
  rengar_main<<<NBLK, TPB, 0, stream>>>(pst_idx, color_sign, sob_sign, wtm,
                                        tempo_w, fs_b, out_va_w, out_fsxva_w,
                                        ws, out);
}

// Round 6
// 835.462 us; speedup vs baseline: 1.1202x; 1.1202x over previous
//
#include <hip/hip_runtime.h>
#include <hip/hip_fp16.h>
#include <stdint.h>

typedef _Float16 f16;
typedef _Float16 f16x8 __attribute__((ext_vector_type(8)));
typedef float f32x4 __attribute__((ext_vector_type(4)));

#define NROWS 262144
#define MROWS 16            // rows per group
#define TPB   768           // 12 waves: each wave owns exactly one table section slice
#define GPB   8             // row-groups per block
#define NBLK  (NROWS / (MROWS * GPB))   // 2048
#define K     192           // padded vocab
#define THR   0.9921875f

// workspace byte offsets (all f16)
#define WS_TABT 0                        // [768][192]
#define WS_W2FS (768 * 192 * 2)          // [16][768]
#define WS_W2VA (WS_W2FS + 16 * 768 * 2) // [16][640]

// LDS layout:
//  cntfx  int  [4][16][192]   @0      (49152)   -- scatter grid (phase A)
//  fsfeat f16  [16][776]      @0      (24832)   -- feature space (reuses grid)
//  vafeat f16  [16][648]      @24832  (20736, ends 45568)
//  cnt16  f16  [4][16][200]   @49152  (25600, ends 74752)  -- packed counts
//  facc/vacc f32 [256]+[256]  @74752  (2048, ends 76800)
#define FS_STRIDE 776
#define VA_STRIDE 648
#define VA_BASE   24832
#define CNT_BASE  49152
#define ACC_BASE  74752
#define SMEM_SZ   76800

__device__ __forceinline__ f16x8 bc8(uint4 u) {
  union { uint4 u; f16x8 h; } x; x.u = u; return x.h;
}
__device__ __forceinline__ float clampv(float x) {
  return fminf(fmaxf(x, -THR), THR);
}
__device__ __forceinline__ uint32_t packh2(float a, float b) {
  union { __half2 h; uint32_t u; } cv; cv.h = __floats2half2_rn(a, b); return cv.u;
}
__device__ __forceinline__ f32x4 chain6(const uint4* af, const uint4* bf) {
  f32x4 a = {0.f, 0.f, 0.f, 0.f};
  #pragma unroll
  for (int ks = 0; ks < 6; ++ks)
    a = __builtin_amdgcn_mfma_f32_16x16x32_f16(bc8(af[ks]), bc8(bf[ks]), a, 0, 0, 0);
  return a;
}

// ---------------- prepack ----------------------------------------------------
__global__ void prepack(const float* __restrict__ emb_fs, const float* __restrict__ emb_va,
                        const float* __restrict__ emb_ha, const float* __restrict__ emb_ra,
                        const float* __restrict__ fs_w,   const float* __restrict__ absva_w,
                        const float* __restrict__ absha_w,const float* __restrict__ absra_w,
                        const float* __restrict__ va_w,   const float* __restrict__ fsxva_w,
                        const float* __restrict__ haxra_w, f16* __restrict__ ws) {
  if (blockIdx.x < 24) {
    __shared__ float tile[192 * 33];
    int u0 = blockIdx.x * 32;
    int t = threadIdx.x;
    #pragma unroll 4
    for (int i = 0; i < 24; ++i) {
      int idx = t + 256 * i;            // 6144 = 192k x 32u
      int k = idx >> 5;
      int c = idx & 31;
      int u = u0 + c;
      float v = 0.f;
      if (k < 185) {
        if      (u < 256) v = emb_fs[k * 256 + u];
        else if (u < 512) v = emb_va[k * 256 + (u - 256)];
        else if (u < 640) v = emb_ha[k * 128 + (u - 512)];
        else              v = emb_ra[k * 128 + (u - 640)];
      }
      tile[k * 33 + c] = v;
    }
    __syncthreads();
    #pragma unroll 4
    for (int i = 0; i < 24; ++i) {
      int idx = t + 256 * i;
      int u = idx / 192;
      int k = idx % 192;
      ws[(u0 + u) * 192 + k] = (f16)tile[k * 33 + u];
    }
  } else {
    int gid = (blockIdx.x - 24) * 256 + threadIdx.x;
    if (gid < 16 * 768) {                        // w2fs[j][k]
      int j = gid / 768, k = gid % 768;
      float v = (k < 256) ? fs_w[j * 256 + k]
              : (k < 512) ? absva_w[j * 256 + (k - 256)]
              : (k < 640) ? absha_w[j * 128 + (k - 512)]
                          : absra_w[j * 128 + (k - 640)];
      ((f16*)((char*)ws + WS_W2FS))[j * 768 + k] = (f16)v;
    } else if (gid < 16 * 768 + 16 * 640) {      // w2va[j][k]
      int g = gid - 16 * 768;
      int j = g / 640, k = g % 640;
      float v = (k < 256) ? va_w[j * 256 + k]
              : (k < 512) ? fsxva_w[j * 256 + (k - 256)]
                          : haxra_w[j * 128 + (k - 512)];
      ((f16*)((char*)ws + WS_W2VA))[j * 640 + k] = (f16)v;
    }
  }
}

// ---------------- main fused kernel ------------------------------------------
// 12 waves/block, 3 waves/EU -> reg cap ~168 (afr1=96 + bfr=24 + acc=16 fits),
// 12 waves/CU occupancy (1.5x the 8-wave variant), no spill.
__global__ __launch_bounds__(TPB, 3)
void rengar_main(const int* __restrict__ pst_idx, const float* __restrict__ color_sign,
                 const float* __restrict__ sob_sign, const float* __restrict__ wtm,
                 const float* __restrict__ tempo_w, const float* __restrict__ fs_b,
                 const float* __restrict__ out_va_w, const float* __restrict__ out_fsxva_w,
                 const f16* __restrict__ ws, float* __restrict__ out) {
  __shared__ __align__(16) char smem[SMEM_SZ];

  const int tid  = threadIdx.x;
  const int lane = tid & 63;
  const int w    = tid >> 6;          // wave 0..11
  const int l15  = lane & 15;
  const int q    = lane >> 4;

  const f16* tabT = (const f16*)((const char*)ws + WS_TABT);
  uint32_t* cnt16 = (uint32_t*)(smem + CNT_BASE);
  float* facc = (float*)(smem + ACC_BASE);
  float* vacc = facc + 256;

  // wave -> table section (tb): waves 0-3 fs, 4-7 va, 8-9 ha, 10-11 ra.
  // 4 tiles/wave, NO wave crosses a section boundary -> single B-set per group.
  const int tb = (w < 4) ? 0 : (w < 8) ? 1 : (w < 10) ? 2 : 3;

  // ---- hoist layer-1 A fragments: 4 tiles/wave = 24 uint4 = 96 regs ----
  uint4 afr1[24];
  #pragma unroll
  for (int i = 0; i < 4; ++i) {
    const f16* ap = tabT + (64 * w + 16 * i + l15) * K + q * 8;
    #pragma unroll
    for (int ks = 0; ks < 6; ++ks) afr1[i * 6 + ks] = *(const uint4*)(ap + ks * 32);
  }

  const int jj = tid & 15;
  const float bj  = fs_b[jj];
  const float w1j = out_va_w[jj];
  const float w2j = out_fsxva_w[jj];

  // ---- prefetch group-0 inputs (512 entries; waves 8-11 idle here) ----
  const int ebase = blockIdx.x * GPB * 512;
  int vidx = 0; float cc = 0.f, ss = 0.f;
  if (tid < 512) {
    vidx = pst_idx[ebase + tid];
    cc   = color_sign[ebase + tid];
    ss   = sob_sign[ebase + tid];
  }
  float wtr = wtm[blockIdx.x * GPB * MROWS + l15];

  // ---- prologue: zero count grid + accumulators (3072 int4 + 128 int4) ----
  {
    int4 z = make_int4(0, 0, 0, 0);
    int4* p = (int4*)smem;
    #pragma unroll
    for (int i = 0; i < 4; ++i) p[tid + 768 * i] = z;
    if (tid < 128) ((int4*)(smem + ACC_BASE))[tid] = z;
  }
  __syncthreads();

  #pragma unroll 1
  for (int g = 0; g < GPB; ++g) {
    const int r0 = (blockIdx.x * GPB + g) * MROWS;

    // ---- P2: scatter (LDS int atomics, scale 2^16) -- grid pre-zeroed
    if (tid < 512) {
      int* base = (int*)smem + (tid >> 5) * K + vidx;
      atomicAdd(base,        65536);
      atomicAdd(base + 3072, __float2int_rn(cc * 65536.f));
      atomicAdd(base + 6144, __float2int_rn(ss * 65536.f));
      atomicAdd(base + 9216, __float2int_rn(cc * ss * 65536.f));
    }
    // prefetch next group's inputs
    float nwt = wtr;
    if (g + 1 < GPB) {
      int nb = ebase + (g + 1) * 512;
      if (tid < 512) {
        vidx = pst_idx[nb + tid];
        cc   = color_sign[nb + tid];
        ss   = sob_sign[nb + tid];
      }
      nwt = wtm[r0 + MROWS + l15];
    }
    __syncthreads();                                       // (1)

    // ---- P3: one-pass convert int grid -> cnt16 (disjoint region)
    {
      const float inv = 1.f / 65536.f;
      const int4* src = (const int4*)smem;
      #pragma unroll
      for (int i = 0; i < 4; ++i) {
        int idx = tid + 768 * i;            // int4 index, lane-consecutive
        int4 t4 = src[idx];
        int tbx = idx / 768;
        int rem = idx - tbx * 768;
        int row = rem / 48;
        int k4  = rem - row * 48;
        uint2 o;
        o.x = packh2((float)t4.x * inv, (float)t4.y * inv);
        o.y = packh2((float)t4.z * inv, (float)t4.w * inv);
        *(uint2*)(cnt16 + tbx * 1600 + row * 100 + k4 * 2) = o;
      }
    }
    __syncthreads();                                       // (2)

    // ---- P4: layer-1 GEMM -- ONE B-set load, 4 independent 6-MFMA chains
    f32x4 acc[4];
    {
      uint4 bfr[6];
      const uint32_t* bp = cnt16 + tb * 1600 + l15 * 100 + q * 4;
      #pragma unroll
      for (int ks = 0; ks < 6; ++ks) bfr[ks] = *(const uint4*)(bp + ks * 16);
      #pragma unroll
      for (int i = 0; i < 4; ++i) acc[i] = chain6(&afr1[i * 6], bfr);
    }
    // ---- P5: clamp + feature store (wave-uniform section, uint2 stores)
    {
      char* fsrow = smem + l15 * (FS_STRIDE * 2);
      char* varow = smem + VA_BASE + l15 * (VA_STRIDE * 2);
      if (tb == 0) {
        #pragma unroll
        for (int i = 0; i < 4; ++i) {
          int m0 = 64 * w + 16 * i + q * 4;
          uint2 o;
          o.x = packh2(clampv(acc[i][0]), clampv(acc[i][1]));
          o.y = packh2(clampv(acc[i][2]), clampv(acc[i][3]));
          *(uint2*)(fsrow + m0 * 2) = o;                       // fs1
        }
      } else if (tb == 1) {
        #pragma unroll
        for (int i = 0; i < 4; ++i) {
          int s0 = 64 * (w - 4) + 16 * i + q * 4;
          float4 tw = *(const float4*)(tempo_w + s0);
          float b0 = clampv(acc[i][0] + wtr * tw.x);
          float b1 = clampv(acc[i][1] + wtr * tw.y);
          float b2 = clampv(acc[i][2] + wtr * tw.z);
          float b3 = clampv(acc[i][3] + wtr * tw.w);
          uint2 o;
          o.x = packh2(b0, b1); o.y = packh2(b2, b3);
          *(uint2*)(varow + s0 * 2) = o;                       // va1
          o.x = packh2(fabsf(b0), fabsf(b1));
          o.y = packh2(fabsf(b2), fabsf(b3));
          *(uint2*)(fsrow + (256 + s0) * 2) = o;               // |va1|
        }
      } else if (tb == 2) {
        #pragma unroll
        for (int i = 0; i < 4; ++i) {
          int s0 = 64 * (w - 8) + 16 * i + q * 4;
          uint2 o;
          o.x = packh2(clampv(acc[i][0]), clampv(acc[i][1]));
          o.y = packh2(clampv(acc[i][2]), clampv(acc[i][3]));
          *(uint2*)(fsrow + (512 + s0) * 2) = o;               // h (signed)
        }
      } else {
        #pragma unroll
        for (int i = 0; i < 4; ++i) {
          int s0 = 64 * (w - 10) + 16 * i + q * 4;
          uint2 o;
          o.x = packh2(clampv(acc[i][0]), clampv(acc[i][1]));
          o.y = packh2(clampv(acc[i][2]), clampv(acc[i][3]));
          *(uint2*)(fsrow + (640 + s0) * 2) = o;               // r (signed)
        }
      }
    }
    __syncthreads();                                       // (3)

    // ---- P6: derived features (cross-wave): fs*va, |h|, |r|, h*r
    {
      uint32_t* fs32 = (uint32_t*)smem;
      uint32_t* va32 = (uint32_t*)(smem + VA_BASE);
      #pragma unroll
      for (int it = 0; it < 4; ++it) {
        int p = tid + 768 * it;
        if (p < 2048) {
          int row = p >> 7, kp = p & 127;
          union { uint32_t u; __half2 h; } a, b, r;
          a.u = fs32[row * 388 + kp];
          b.u = va32[row * 324 + kp];
          r.h = __hmul2(a.h, b.h);
          va32[row * 324 + 128 + kp] = r.u;
        } else {
          int pc = p - 2048;
          int row = pc >> 6, kp = pc & 63;
          union { uint32_t u; __half2 h; } h2, r2, pr;
          h2.u = fs32[row * 388 + 256 + kp];
          r2.u = fs32[row * 388 + 320 + kp];
          pr.h = __hmul2(h2.h, r2.h);
          fs32[row * 388 + 256 + kp] = h2.u & 0x7FFF7FFFu;
          fs32[row * 388 + 320 + kp] = r2.u & 0x7FFF7FFFu;
          va32[row * 324 + 256 + kp] = pr.u;
        }
      }
    }
    __syncthreads();                                       // (4)

    // ---- P7: layer-2 split-K over 12 waves (fs: 6x128, va: 4x128 + 2x64),
    //      A streamed from L1/L2 (same addresses every group), LDS f32 atomics
    {
      f32x4 acc2 = {0.f, 0.f, 0.f, 0.f};
      if (w < 6) {
        const f16* A = (const f16*)((const char*)ws + WS_W2FS) + l15 * 768 + w * 128 + q * 8;
        const char* frow = smem + l15 * (FS_STRIDE * 2);
        uint4 a0 = *(const uint4*)(A);
        uint4 a1 = *(const uint4*)(A + 32);
        uint4 a2v = *(const uint4*)(A + 64);
        uint4 a3 = *(const uint4*)(A + 96);
        uint4 b0 = *(const uint4*)(frow + (w * 128 +  0 + q * 8) * 2);
        uint4 b1 = *(const uint4*)(frow + (w * 128 + 32 + q * 8) * 2);
        uint4 b2 = *(const uint4*)(frow + (w * 128 + 64 + q * 8) * 2);
        uint4 b3 = *(const uint4*)(frow + (w * 128 + 96 + q * 8) * 2);
        acc2 = __builtin_amdgcn_mfma_f32_16x16x32_f16(bc8(a0), bc8(b0), acc2, 0, 0, 0);
        acc2 = __builtin_amdgcn_mfma_f32_16x16x32_f16(bc8(a1), bc8(b1), acc2, 0, 0, 0);
        acc2 = __builtin_amdgcn_mfma_f32_16x16x32_f16(bc8(a2v), bc8(b2), acc2, 0, 0, 0);
        acc2 = __builtin_amdgcn_mfma_f32_16x16x32_f16(bc8(a3), bc8(b3), acc2, 0, 0, 0);
        int base = l15 << 4;
        #pragma unroll
        for (int r = 0; r < 4; ++r) {
          int j = q * 4 + r;
          atomicAdd(&facc[base + ((j + l15) & 15)], acc2[r]);
        }
      } else if (w < 10) {
        const f16* A = (const f16*)((const char*)ws + WS_W2VA) + l15 * 640 + (w - 6) * 128 + q * 8;
        const char* vrow = smem + VA_BASE + l15 * (VA_STRIDE * 2);
        uint4 a0 = *(const uint4*)(A);
        uint4 a1 = *(const uint4*)(A + 32);
        uint4 a2v = *(const uint4*)(A + 64);
        uint4 a3 = *(const uint4*)(A + 96);
        uint4 b0 = *(const uint4*)(vrow + ((w - 6) * 128 +  0 + q * 8) * 2);
        uint4 b1 = *(const uint4*)(vrow + ((w - 6) * 128 + 32 + q * 8) * 2);
        uint4 b2 = *(const uint4*)(vrow + ((w - 6) * 128 + 64 + q * 8) * 2);
        uint4 b3 = *(const uint4*)(vrow + ((w - 6) * 128 + 96 + q * 8) * 2);
        acc2 = __builtin_amdgcn_mfma_f32_16x16x32_f16(bc8(a0), bc8(b0), acc2, 0, 0, 0);
        acc2 = __builtin_amdgcn_mfma_f32_16x16x32_f16(bc8(a1), bc8(b1), acc2, 0, 0, 0);
        acc2 = __builtin_amdgcn_mfma_f32_16x16x32_f16(bc8(a2v), bc8(b2), acc2, 0, 0, 0);
        acc2 = __builtin_amdgcn_mfma_f32_16x16x32_f16(bc8(a3), bc8(b3), acc2, 0, 0, 0);
        int base = l15 << 4;
        #pragma unroll
        for (int r = 0; r < 4; ++r) {
          int j = q * 4 + r;
          atomicAdd(&vacc[base + ((j + l15) & 15)], acc2[r]);
        }
      } else {
        const f16* A = (const f16*)((const char*)ws + WS_W2VA) + l15 * 640 + 512 + (w - 10) * 64 + q * 8;
        const char* vrow = smem + VA_BASE + l15 * (VA_STRIDE * 2);
        uint4 a0 = *(const uint4*)(A);
        uint4 a1 = *(const uint4*)(A + 32);
        uint4 b0 = *(const uint4*)(vrow + (512 + (w - 10) * 64 +  0 + q * 8) * 2);
        uint4 b1 = *(const uint4*)(vrow + (512 + (w - 10) * 64 + 32 + q * 8) * 2);
        acc2 = __builtin_amdgcn_mfma_f32_16x16x32_f16(bc8(a0), bc8(b0), acc2, 0, 0, 0);
        acc2 = __builtin_amdgcn_mfma_f32_16x16x32_f16(bc8(a1), bc8(b1), acc2, 0, 0, 0);
        int base = l15 << 4;
        #pragma unroll
        for (int r = 0; r < 4; ++r) {
          int j = q * 4 + r;
          atomicAdd(&vacc[base + ((j + l15) & 15)], acc2[r]);
        }
      }
    }
    __syncthreads();                                       // (5)

    // ---- P8: threads 0-255: read accum (+re-zero), bias/clamp, shfl reduce,
    //      output. Threads 256-767: re-zero the count grid for next group.
    if (tid < 256) {
      int b = tid >> 4;
      int idx = (b << 4) | ((jj + b) & 15);
      float f = facc[idx];
      float v = vacc[idx];
      facc[idx] = 0.f;
      vacc[idx] = 0.f;
      f = clampv(f + bj);
      v = clampv(v);
      float rr = v * w1j + f * v * w2j;
      rr += __shfl_xor(rr, 1);
      rr += __shfl_xor(rr, 2);
      rr += __shfl_xor(rr, 4);
      rr += __shfl_xor(rr, 8);
      if (jj == 0) out[r0 + b] = rr;
    } else if (g + 1 < GPB) {
      int4 z = make_int4(0, 0, 0, 0);
      int4* p = (int4*)smem;
      int t2 = tid - 256;
      #pragma unroll
      for (int i = 0; i < 6; ++i) p[t2 + 512 * i] = z;     // grid 0..49152
    }
    __syncthreads();                                       // (6)
    wtr = nwt;
  }
}

extern "C" void kernel_launch(void* const* d_in, const int* in_sizes, int n_in,
                              void* d_out, int out_size, void* d_ws, size_t ws_size,
                              hipStream_t stream) {
  const int*   pst_idx     = (const int*)  d_in[0];
  const float* color_sign  = (const float*)d_in[1];
  const float* sob_sign    = (const float*)d_in[2];
  const float* wtm         = (const float*)d_in[3];
  const float* emb_fs      = (const float*)d_in[4];
  const float* emb_va      = (const float*)d_in[5];
  const float* emb_ha      = (const float*)d_in[6];
  const float* emb_ra      = (const float*)d_in[7];
  const float* tempo_w     = (const float*)d_in[8];
  const float* fs_b        = (const float*)d_in[10];
  const float* fs_w        = (const float*)d_in[9];
  const float* absva_w     = (const float*)d_in[11];
  const float* absha_w     = (const float*)d_in[12];
  const float* absra_w     = (const float*)d_in[13];
  const float* va_w        = (const float*)d_in[14];
  const float* fsxva_w     = (const float*)d_in[15];
  const float* haxra_w     = (const float*)d_in[16];
  const float* out_va_w    = (const float*)d_in[17];
  const float* out_fsxva_w = (const float*)d_in[18];
  float* out = (float*)d_out;
  f16* ws = (f16*)d_ws;

  prepack<<<24 + 88, 256, 0, stream>>>(emb_fs, emb_va, emb_ha, emb_ra,
                                       fs_w, absva_w, absha_w, absra_w,
                                       va_w, fsxva_w, haxra_w, ws);
  rengar_main<<<NBLK, TPB, 0, stream>>>(pst_idx, color_sign, sob_sign, wtm,
                                        tempo_w, fs_b, out_va_w, out_fsxva_w,
                                        ws, out);
}

// Round 7
// 732.468 us; speedup vs baseline: 1.2777x; 1.1406x over previous
//
#include <hip/hip_runtime.h>
#include <hip/hip_fp16.h>
#include <stdint.h>

typedef _Float16 f16;
typedef _Float16 f16x8 __attribute__((ext_vector_type(8)));
typedef float f32x4 __attribute__((ext_vector_type(4)));

#define NROWS 262144
#define MROWS 16            // rows per group
#define TPB   512           // 8 waves
#define GPB   8             // row-groups per block (table reused across these)
#define NBLK  (NROWS / (MROWS * GPB))   // 2048
#define K     192           // padded vocab
#define THR   0.9921875f

// workspace byte offsets (all f16)
#define WS_TABT 0                        // [768][192]
#define WS_W2FS (768 * 192 * 2)          // [16][768]
#define WS_W2VA (WS_W2FS + 16 * 768 * 2) // [16][640]

// LDS layout (1 block/CU):
//  cntfx  int  [4][16][192]   @0      (49152)   -- scatter grid (phase A)
//  fsfeat f16  [16][776]      @0      (24832)   -- feature space (reuses grid)
//  vafeat f16  [16][648]      @24832  (20736, ends 45568)
//  cnt16  f16  [4][16][200]   @49152  (25600, ends 74752)  -- packed counts
//  facc/vacc f32 [256]+[256]  @74752  (2048, ends 76800)
#define FS_STRIDE 776
#define VA_STRIDE 648
#define VA_BASE   24832
#define CNT_BASE  49152
#define ACC_BASE  74752
#define SMEM_SZ   76800

__device__ __forceinline__ f16x8 bc8(uint4 u) {
  union { uint4 u; f16x8 h; } x; x.u = u; return x.h;
}
__device__ __forceinline__ float clampv(float x) {
  return fminf(fmaxf(x, -THR), THR);
}
__device__ __forceinline__ uint32_t packh2(float a, float b) {
  union { __half2 h; uint32_t u; } cv; cv.h = __floats2half2_rn(a, b); return cv.u;
}

// ---------------- prepack ----------------------------------------------------
__global__ void prepack(const float* __restrict__ emb_fs, const float* __restrict__ emb_va,
                        const float* __restrict__ emb_ha, const float* __restrict__ emb_ra,
                        const float* __restrict__ fs_w,   const float* __restrict__ absva_w,
                        const float* __restrict__ absha_w,const float* __restrict__ absra_w,
                        const float* __restrict__ va_w,   const float* __restrict__ fsxva_w,
                        const float* __restrict__ haxra_w, f16* __restrict__ ws) {
  if (blockIdx.x < 24) {
    __shared__ float tile[192 * 33];
    int u0 = blockIdx.x * 32;
    int t = threadIdx.x;
    #pragma unroll 4
    for (int i = 0; i < 24; ++i) {
      int idx = t + 256 * i;            // 6144 = 192k x 32u
      int k = idx >> 5;
      int c = idx & 31;
      int u = u0 + c;
      float v = 0.f;
      if (k < 185) {
        if      (u < 256) v = emb_fs[k * 256 + u];
        else if (u < 512) v = emb_va[k * 256 + (u - 256)];
        else if (u < 640) v = emb_ha[k * 128 + (u - 512)];
        else              v = emb_ra[k * 128 + (u - 640)];
      }
      tile[k * 33 + c] = v;
    }
    __syncthreads();
    #pragma unroll 4
    for (int i = 0; i < 24; ++i) {
      int idx = t + 256 * i;
      int u = idx / 192;
      int k = idx % 192;
      ws[(u0 + u) * 192 + k] = (f16)tile[k * 33 + u];
    }
  } else {
    int gid = (blockIdx.x - 24) * 256 + threadIdx.x;
    if (gid < 16 * 768) {                        // w2fs[j][k]
      int j = gid / 768, k = gid % 768;
      float v = (k < 256) ? fs_w[j * 256 + k]
              : (k < 512) ? absva_w[j * 256 + (k - 256)]
              : (k < 640) ? absha_w[j * 128 + (k - 512)]
                          : absra_w[j * 128 + (k - 640)];
      ((f16*)((char*)ws + WS_W2FS))[j * 768 + k] = (f16)v;
    } else if (gid < 16 * 768 + 16 * 640) {      // w2va[j][k]
      int g = gid - 16 * 768;
      int j = g / 640, k = g % 640;
      float v = (k < 256) ? va_w[j * 256 + k]
              : (k < 512) ? fsxva_w[j * 256 + (k - 256)]
                          : haxra_w[j * 128 + (k - 512)];
      ((f16*)((char*)ws + WS_W2VA))[j * 640 + k] = (f16)v;
    }
  }
}

// ---------------- main fused kernel ------------------------------------------
// 2 waves/EU, 1 block/CU: the ONLY regime where the resident table fits
// (rounds 1/3/5/6 all spilled above this). Optimize the serial path instead.
__global__ __launch_bounds__(TPB, 2)
void rengar_main(const int* __restrict__ pst_idx, const float* __restrict__ color_sign,
                 const float* __restrict__ sob_sign, const float* __restrict__ wtm,
                 const float* __restrict__ tempo_w, const float* __restrict__ fs_b,
                 const float* __restrict__ out_va_w, const float* __restrict__ out_fsxva_w,
                 const f16* __restrict__ ws, float* __restrict__ out) {
  __shared__ __align__(16) char smem[SMEM_SZ];

  const int tid  = threadIdx.x;
  const int lane = tid & 63;
  const int w    = tid >> 6;          // wave 0..7
  const int l15  = lane & 15;
  const int q    = lane >> 4;

  const f16* tabT = (const f16*)((const char*)ws + WS_TABT);
  uint32_t* cnt16 = (uint32_t*)(smem + CNT_BASE);
  float* facc = (float*)(smem + ACC_BASE);
  float* vacc = facc + 256;

  // ---- hoist layer-1 A fragments: 6 tiles/wave (round-0 map, verbatim) ----
  uint4 afr1[36];
  int   tbs[6];
  #pragma unroll
  for (int i = 0; i < 6; ++i) {
    int t  = w * 6 + i;
    int u0 = t * 16;
    tbs[i] = (u0 < 256) ? 0 : (u0 < 512) ? 1 : (u0 < 640) ? 2 : 3;
    const f16* ap = tabT + (u0 + l15) * K + q * 8;
    #pragma unroll
    for (int ks = 0; ks < 6; ++ks) afr1[i * 6 + ks] = *(const uint4*)(ap + ks * 32);
  }

  // ---- hoist layer-2 A fragments (split-K: fs -> waves 0-3, va -> waves 4-7)
  uint4 a2[6];
  if (w < 4) {
    const f16* A = (const f16*)((const char*)ws + WS_W2FS) + l15 * 768 + w * 192 + q * 8;
    #pragma unroll
    for (int ks = 0; ks < 6; ++ks) a2[ks] = *(const uint4*)(A + ks * 32);
  } else {
    const f16* A = (const f16*)((const char*)ws + WS_W2VA) + l15 * 640 + (w - 4) * 160 + q * 8;
    #pragma unroll
    for (int ks = 0; ks < 5; ++ks) a2[ks] = *(const uint4*)(A + ks * 32);
  }

  const int jj = tid & 15;
  float bj = 0.f, w1j = 0.f, w2j = 0.f;
  if (tid < 256) {
    bj  = fs_b[jj];
    w1j = out_va_w[jj];
    w2j = out_fsxva_w[jj];
  }

  // ---- prefetch group-0 inputs ----
  const int ebase = blockIdx.x * GPB * 512;
  int   vidx = pst_idx[ebase + tid];
  float cc   = color_sign[ebase + tid];
  float ss   = sob_sign[ebase + tid];
  float wtr  = wtm[blockIdx.x * GPB * MROWS + l15];

  // ---- prologue: zero count grid + accumulators ----
  {
    int4 z = make_int4(0, 0, 0, 0);
    int4* p = (int4*)smem;
    #pragma unroll
    for (int i = 0; i < 6; ++i) p[tid + 512 * i] = z;           // grid 0..49152
    if (tid < 128) ((int4*)(smem + ACC_BASE))[tid] = z;         // facc/vacc
  }
  __syncthreads();

  #pragma unroll 1
  for (int g = 0; g < GPB; ++g) {
    const int r0 = (blockIdx.x * GPB + g) * MROWS;

    // ---- P2: scatter (LDS int atomics, scale 2^16) -- grid pre-zeroed
    {
      int* base = (int*)smem + (tid >> 5) * K + vidx;
      atomicAdd(base + 0 * MROWS * K, 65536);
      atomicAdd(base + 1 * MROWS * K, __float2int_rn(cc * 65536.f));
      atomicAdd(base + 2 * MROWS * K, __float2int_rn(ss * 65536.f));
      atomicAdd(base + 3 * MROWS * K, __float2int_rn(cc * ss * 65536.f));
    }
    __syncthreads();                                       // (1)

    // ---- P3: one-pass convert int grid -> cnt16 (disjoint region, no WAR)
    {
      const float inv = 1.f / 65536.f;
      const int4* src = (const int4*)smem;
      #pragma unroll
      for (int i = 0; i < 6; ++i) {
        int idx = tid + 512 * i;            // int4 index, lane-consecutive reads
        int4 t4 = src[idx];
        int tb  = idx / 768;
        int rem = idx - tb * 768;
        int row = rem / 48;
        int k4  = rem - row * 48;
        uint2 o;
        o.x = packh2((float)t4.x * inv, (float)t4.y * inv);
        o.y = packh2((float)t4.z * inv, (float)t4.w * inv);
        *(uint2*)(cnt16 + tb * 1600 + row * 100 + k4 * 2) = o;  // lane-consecutive
      }
    }
    __syncthreads();                                       // (2)

    // ---- P4: layer-1 GEMM (round-0 verbatim: 6 independent chains) ----
    //      + next-group input prefetch issued HERE so the HBM latency drains
    //        under P4/P5 work instead of at the post-scatter barrier.
    float nwt = wtr;
    f32x4 acc[6];
    {
      uint4 bfr[6];
      int tb_cur = -1;
      if (g + 1 < GPB) {
        int nb = ebase + (g + 1) * 512;
        vidx = pst_idx[nb + tid];
        cc   = color_sign[nb + tid];
        ss   = sob_sign[nb + tid];
        nwt  = wtm[r0 + MROWS + l15];
      }
      #pragma unroll
      for (int i = 0; i < 6; ++i) {
        int tb = tbs[i];
        if (tb != tb_cur) {
          tb_cur = tb;
          #pragma unroll
          for (int ks = 0; ks < 6; ++ks) {
            const uint32_t* p = cnt16 + tb * 1600 + l15 * 100 + ks * 16 + q * 4;
            bfr[ks] = *(const uint4*)p;
          }
        }
        f32x4 a = {0.f, 0.f, 0.f, 0.f};
        #pragma unroll
        for (int ks = 0; ks < 6; ++ks)
          a = __builtin_amdgcn_mfma_f32_16x16x32_f16(bc8(afr1[i * 6 + ks]), bc8(bfr[ks]), a, 0, 0, 0);
        acc[i] = a;
      }
    }
    // ---- P5 (round-0 verbatim): features; no barrier needed since cnt16
    //      region (49152..) is disjoint from the feature region (0..45568).
    {
      #pragma unroll
      for (int i = 0; i < 6; ++i) {
        int t  = w * 6 + i;
        int u0 = t * 16;
        int tb = tbs[i];
        int m0 = u0 + q * 4;
        f32x4 a = acc[i];
        if (tb == 0) {
          __half2* d = (__half2*)(smem + l15 * (FS_STRIDE * 2) + m0 * 2);
          d[0] = __floats2half2_rn(clampv(a[0]), clampv(a[1]));
          d[1] = __floats2half2_rn(clampv(a[2]), clampv(a[3]));
        } else if (tb == 1) {
          int s0 = m0 - 256;
          float4 tw = *(const float4*)(tempo_w + s0);
          float b0 = clampv(a[0] + wtr * tw.x);
          float b1 = clampv(a[1] + wtr * tw.y);
          float b2 = clampv(a[2] + wtr * tw.z);
          float b3 = clampv(a[3] + wtr * tw.w);
          __half2* dv = (__half2*)(smem + VA_BASE + l15 * (VA_STRIDE * 2) + s0 * 2);
          dv[0] = __floats2half2_rn(b0, b1);
          dv[1] = __floats2half2_rn(b2, b3);
          __half2* df = (__half2*)(smem + l15 * (FS_STRIDE * 2) + (256 + s0) * 2);
          df[0] = __floats2half2_rn(fabsf(b0), fabsf(b1));
          df[1] = __floats2half2_rn(fabsf(b2), fabsf(b3));
        } else if (tb == 2) {
          int s0 = m0 - 512;
          __half2* d = (__half2*)(smem + l15 * (FS_STRIDE * 2) + (512 + s0) * 2);
          d[0] = __floats2half2_rn(clampv(a[0]), clampv(a[1]));
          d[1] = __floats2half2_rn(clampv(a[2]), clampv(a[3]));
        } else {
          int s0 = m0 - 640;
          __half2* d = (__half2*)(smem + l15 * (FS_STRIDE * 2) + (640 + s0) * 2);
          d[0] = __floats2half2_rn(clampv(a[0]), clampv(a[1]));
          d[1] = __floats2half2_rn(clampv(a[2]), clampv(a[3]));
        }
      }
    }
    __syncthreads();                                       // (3)

    // ---- P6 (round-0 verbatim): derived features: ab, |h|, |r|, h*r
    {
      uint32_t* fs32 = (uint32_t*)smem;
      uint32_t* va32 = (uint32_t*)(smem + VA_BASE);
      #pragma unroll
      for (int it = 0; it < 6; ++it) {
        int p = tid + 512 * it;
        if (p < 2048) {
          int row = p >> 7, kp = p & 127;
          union { uint32_t u; __half2 h; } a, b, r;
          a.u = fs32[row * 388 + kp];
          b.u = va32[row * 324 + kp];
          r.h = __hmul2(a.h, b.h);
          va32[row * 324 + 128 + kp] = r.u;
        } else {
          int pc = p - 2048;
          int row = pc >> 6, kp = pc & 63;
          union { uint32_t u; __half2 h; } h2, r2, pr;
          h2.u = fs32[row * 388 + 256 + kp];
          r2.u = fs32[row * 388 + 320 + kp];
          pr.h = __hmul2(h2.h, r2.h);
          fs32[row * 388 + 256 + kp] = h2.u & 0x7FFF7FFFu;
          fs32[row * 388 + 320 + kp] = r2.u & 0x7FFF7FFFu;
          va32[row * 324 + 256 + kp] = pr.u;
        }
      }
    }
    __syncthreads();                                       // (4)

    // ---- P7: layer-2 split-K across all 8 waves, LDS f32 atomic combine
    {
      f32x4 a2acc = {0.f, 0.f, 0.f, 0.f};
      if (w < 4) {
        #pragma unroll
        for (int ks = 0; ks < 6; ++ks) {
          int k = w * 192 + ks * 32 + q * 8;
          uint4 bf = *(const uint4*)(smem + l15 * (FS_STRIDE * 2) + k * 2);
          a2acc = __builtin_amdgcn_mfma_f32_16x16x32_f16(bc8(a2[ks]), bc8(bf), a2acc, 0, 0, 0);
        }
      } else {
        #pragma unroll
        for (int ks = 0; ks < 5; ++ks) {
          int k = (w - 4) * 160 + ks * 32 + q * 8;
          uint4 bf = *(const uint4*)(smem + VA_BASE + l15 * (VA_STRIDE * 2) + k * 2);
          a2acc = __builtin_amdgcn_mfma_f32_16x16x32_f16(bc8(a2[ks]), bc8(bf), a2acc, 0, 0, 0);
        }
      }
      float* dstacc = (w < 4) ? facc : vacc;
      int base = l15 << 4;               // l15 = batch row (D col)
      #pragma unroll
      for (int r = 0; r < 4; ++r) {
        int j = q * 4 + r;               // output index
        atomicAdd(&dstacc[base + ((j + l15) & 15)], a2acc[r]);  // staggered banks
      }
    }
    __syncthreads();                                       // (5)

    // ---- P8: waves 0-3: read accum (+re-zero), bias/clamp, shfl reduce, out.
    //          waves 4-7: re-zero the 48 KiB count grid for the next group.
    if (tid < 256) {
      int b = tid >> 4;
      int idx = (b << 4) | ((jj + b) & 15);
      float f = facc[idx];
      float v = vacc[idx];
      facc[idx] = 0.f;
      vacc[idx] = 0.f;
      f = clampv(f + bj);
      v = clampv(v);
      float rr = v * w1j + f * v * w2j;
      rr += __shfl_xor(rr, 1);
      rr += __shfl_xor(rr, 2);
      rr += __shfl_xor(rr, 4);
      rr += __shfl_xor(rr, 8);
      if (jj == 0) out[r0 + b] = rr;
    } else if (g + 1 < GPB) {
      int4 z = make_int4(0, 0, 0, 0);
      int4* p = (int4*)smem;
      int t2 = tid - 256;
      #pragma unroll
      for (int i = 0; i < 12; ++i) p[t2 + 256 * i] = z;    // grid 0..49152
    }
    __syncthreads();                                       // (6)
    wtr = nwt;
  }
}

extern "C" void kernel_launch(void* const* d_in, const int* in_sizes, int n_in,
                              void* d_out, int out_size, void* d_ws, size_t ws_size,
                              hipStream_t stream) {
  const int*   pst_idx     = (const int*)  d_in[0];
  const float* color_sign  = (const float*)d_in[1];
  const float* sob_sign    = (const float*)d_in[2];
  const float* wtm         = (const float*)d_in[3];
  const float* emb_fs      = (const float*)d_in[4];
  const float* emb_va      = (const float*)d_in[5];
  const float* emb_ha      = (const float*)d_in[6];
  const float* emb_ra      = (const float*)d_in[7];
  const float* tempo_w     = (const float*)d_in[8];
  const float* fs_b        = (const float*)d_in[10];
  const float* fs_w        = (const float*)d_in[9];
  const float* absva_w     = (const float*)d_in[11];
  const float* absha_w     = (const float*)d_in[12];
  const float* absra_w     = (const float*)d_in[13];
  const float* va_w        = (const float*)d_in[14];
  const float* fsxva_w     = (const float*)d_in[15];
  const float* haxra_w     = (const float*)d_in[16];
  const float* out_va_w    = (const float*)d_in[17];
  const float* out_fsxva_w = (const float*)d_in[18];
  float* out = (float*)d_out;
  f16* ws = (f16*)d_ws;

  prepack<<<24 + 88, 256, 0, stream>>>(emb_fs, emb_va, emb_ha, emb_ra,
                                       fs_w, absva_w, absha_w, absra_w,
                                       va_w, fsxva_w, haxra_w, ws);
  rengar_main<<<NBLK, TPB, 0, stream>>>(pst_idx, color_sign, sob_sign, wtm,
                                        tempo_w, fs_b, out_va_w, out_fsxva_w,
                                        ws, out);
}

// Round 9
// 511.337 us; speedup vs baseline: 1.8302x; 1.4325x over previous
//
#include <hip/hip_runtime.h>
#include <hip/hip_fp16.h>
#include <stdint.h>

typedef _Float16 f16;
typedef _Float16 f16x8 __attribute__((ext_vector_type(8)));
typedef float f32x4 __attribute__((ext_vector_type(4)));

#define NROWS 262144
#define MROWS 16            // rows per group
#define TPB   512           // 8 waves
#define GPB   16            // row-groups per block (table reused across these)
#define NBLK  (NROWS / (MROWS * GPB))   // 1024
#define K     192           // padded vocab
#define THR   0.9921875f

// workspace byte offsets (all f16)
#define WS_TABT 0                        // [768][192]
#define WS_W2FS (768 * 192 * 2)          // [16][768]
#define WS_W2VA (WS_W2FS + 16 * 768 * 2) // [16][640]

// LDS layout (time-multiplexed):
//  phase A: cntfx  int  [4][16][192]         @0      (49152)
//  phase B: cnt16  f16  [4][16][200]         @0      (25600)
//  phase C: fsfeat f16  [16][776]            @0      (24832)
//           vafeat f16  [16][648]            @24832  (20736)
//           exch   f32  [8][16][16]          @45568  (8192)
//           prod   f32  [16][16]             @53760  (1024)
#define FS_STRIDE 776
#define VA_STRIDE 648
#define VA_BASE   24832
#define EX_BASE   45568
#define PROD_BASE 53760
#define SMEM_SZ   54784

__device__ __forceinline__ f16x8 bc8(uint4 u) {
  union { uint4 u; f16x8 h; } x; x.u = u; return x.h;
}
__device__ __forceinline__ float clampv(float x) {
  return fminf(fmaxf(x, -THR), THR);
}

// ---------------- prepack ----------------------------------------------------
// blocks 0..23: table transpose via LDS tile (coalesced both sides)
// blocks 24.. : layer-2 weight pack (already coalesced)
__global__ void prepack(const float* __restrict__ emb_fs, const float* __restrict__ emb_va,
                        const float* __restrict__ emb_ha, const float* __restrict__ emb_ra,
                        const float* __restrict__ fs_w,   const float* __restrict__ absva_w,
                        const float* __restrict__ absha_w,const float* __restrict__ absra_w,
                        const float* __restrict__ va_w,   const float* __restrict__ fsxva_w,
                        const float* __restrict__ haxra_w, f16* __restrict__ ws) {
  if (blockIdx.x < 24) {
    __shared__ float tile[192 * 33];
    int u0 = blockIdx.x * 32;
    int t = threadIdx.x;
    #pragma unroll 4
    for (int i = 0; i < 24; ++i) {
      int idx = t + 256 * i;            // 6144 = 192k x 32u
      int k = idx >> 5;
      int c = idx & 31;
      int u = u0 + c;
      float v = 0.f;
      if (k < 185) {
        if      (u < 256) v = emb_fs[k * 256 + u];
        else if (u < 512) v = emb_va[k * 256 + (u - 256)];
        else if (u < 640) v = emb_ha[k * 128 + (u - 512)];
        else              v = emb_ra[k * 128 + (u - 640)];
      }
      tile[k * 33 + c] = v;
    }
    __syncthreads();
    #pragma unroll 4
    for (int i = 0; i < 24; ++i) {
      int idx = t + 256 * i;
      int u = idx / 192;
      int k = idx % 192;
      ws[(u0 + u) * 192 + k] = (f16)tile[k * 33 + u];
    }
  } else {
    int gid = (blockIdx.x - 24) * 256 + threadIdx.x;
    if (gid < 16 * 768) {                        // w2fs[j][k]
      int j = gid / 768, k = gid % 768;
      float v = (k < 256) ? fs_w[j * 256 + k]
              : (k < 512) ? absva_w[j * 256 + (k - 256)]
              : (k < 640) ? absha_w[j * 128 + (k - 512)]
                          : absra_w[j * 128 + (k - 640)];
      ((f16*)((char*)ws + WS_W2FS))[j * 768 + k] = (f16)v;
    } else if (gid < 16 * 768 + 16 * 640) {      // w2va[j][k]
      int g = gid - 16 * 768;
      int j = g / 640, k = g % 640;
      float v = (k < 256) ? va_w[j * 256 + k]
              : (k < 512) ? fsxva_w[j * 256 + (k - 256)]
                          : haxra_w[j * 128 + (k - 512)];
      ((f16*)((char*)ws + WS_W2VA))[j * 640 + k] = (f16)v;
    }
  }
}

// ---------------- main fused kernel ------------------------------------------
__global__ __launch_bounds__(TPB, 2)
void rengar_main(const int* __restrict__ pst_idx, const float* __restrict__ color_sign,
                 const float* __restrict__ sob_sign, const float* __restrict__ wtm,
                 const float* __restrict__ tempo_w, const float* __restrict__ fs_b,
                 const float* __restrict__ out_va_w, const float* __restrict__ out_fsxva_w,
                 const f16* __restrict__ ws, float* __restrict__ out) {
  __shared__ __align__(16) char smem[SMEM_SZ];

  const int tid  = threadIdx.x;
  const int lane = tid & 63;
  const int w    = tid >> 6;          // wave 0..7
  const int l15  = lane & 15;
  const int q    = lane >> 4;

  const f16* tabT = (const f16*)((const char*)ws + WS_TABT);

  // ---- hoist layer-1 A fragments: 6 tiles/wave, reused across all groups ----
  uint4 afr1[36];
  int   tbs[6];
  #pragma unroll
  for (int i = 0; i < 6; ++i) {
    int t  = w * 6 + i;
    int u0 = t * 16;
    tbs[i] = (u0 < 256) ? 0 : (u0 < 512) ? 1 : (u0 < 640) ? 2 : 3;
    const f16* ap = tabT + (u0 + l15) * K + q * 8;
    #pragma unroll
    for (int ks = 0; ks < 6; ++ks) afr1[i * 6 + ks] = *(const uint4*)(ap + ks * 32);
  }

  // ---- hoist layer-2 A fragments (split-K: fs -> waves 0-3, va -> waves 4-7)
  uint4 a2[6];
  if (w < 4) {
    const f16* A = (const f16*)((const char*)ws + WS_W2FS) + l15 * 768 + w * 192 + q * 8;
    #pragma unroll
    for (int ks = 0; ks < 6; ++ks) a2[ks] = *(const uint4*)(A + ks * 32);
  } else {
    const f16* A = (const f16*)((const char*)ws + WS_W2VA) + l15 * 640 + (w - 4) * 160 + q * 8;
    #pragma unroll
    for (int ks = 0; ks < 5; ++ks) a2[ks] = *(const uint4*)(A + ks * 32);
  }

  float bj = 0.f, w1j = 0.f, w2j = 0.f;
  if (tid < 256) {
    int j = tid >> 4;
    bj  = fs_b[j];
    w1j = out_va_w[j];
    w2j = out_fsxva_w[j];
  }

  // ---- prefetch group-0 inputs ----
  const int ebase = blockIdx.x * GPB * 512;
  int   vidx = pst_idx[ebase + tid];
  float cc   = color_sign[ebase + tid];
  float ss   = sob_sign[ebase + tid];
  float wtr  = wtm[blockIdx.x * GPB * MROWS + l15];

  // ---- prologue: zero count grid once (in-loop re-zero happens in P8) ----
  {
    int4 z = make_int4(0, 0, 0, 0);
    int4* p = (int4*)smem;
    #pragma unroll
    for (int i = 0; i < 6; ++i) p[tid + 512 * i] = z;
  }
  __syncthreads();

  #pragma unroll 1
  for (int g = 0; g < GPB; ++g) {
    const int r0 = (blockIdx.x * GPB + g) * MROWS;

    // ---- P2: scatter (LDS int atomics, scale 2^16) -- grid pre-zeroed
    {
      int* cntfx = (int*)smem;
      int  row = tid >> 5;
      int* base = cntfx + row * K + vidx;
      atomicAdd(base + 0 * MROWS * K, 65536);
      atomicAdd(base + 1 * MROWS * K, __float2int_rn(cc * 65536.f));
      atomicAdd(base + 2 * MROWS * K, __float2int_rn(ss * 65536.f));
      atomicAdd(base + 3 * MROWS * K, __float2int_rn(cc * ss * 65536.f));
    }
    // prefetch next group's inputs (latency hidden behind this group's work)
    float nwt = wtr;
    if (g + 1 < GPB) {
      int nb = ebase + (g + 1) * 512;
      vidx = pst_idx[nb + tid];
      cc   = color_sign[nb + tid];
      ss   = sob_sign[nb + tid];
      nwt  = wtm[r0 + MROWS + l15];
    }
    __syncthreads();

    // ---- P3: convert int -> f16 counts, re-layout [tb][row][200-u32-stride-100]
    {
      int vals[24];
      const int4* src = (const int4*)smem;
      #pragma unroll
      for (int i = 0; i < 6; ++i) {
        int4 t4 = src[tid * 6 + i];
        vals[4 * i + 0] = t4.x; vals[4 * i + 1] = t4.y;
        vals[4 * i + 2] = t4.z; vals[4 * i + 3] = t4.w;
      }
      __syncthreads();
      int lin = 24 * tid;
      int tb  = lin / 3072;
      int row = (lin / 192) & 15;
      int k0  = lin % 192;
      uint32_t* dst = (uint32_t*)smem + tb * 1600 + row * 100 + (k0 >> 1);
      const float inv = 1.f / 65536.f;
      #pragma unroll
      for (int i = 0; i < 12; ++i) {
        __half2 h = __floats2half2_rn(vals[2 * i] * inv, vals[2 * i + 1] * inv);
        union { __half2 h; uint32_t u; } cv; cv.h = h;
        dst[i] = cv.u;
      }
    }
    __syncthreads();

    // ---- P4: layer-1 GEMM (A register-resident, B from LDS counts)
    f32x4 acc[6];
    {
      uint4 bfr[6];
      int tb_cur = -1;
      #pragma unroll
      for (int i = 0; i < 6; ++i) {
        int tb = tbs[i];
        if (tb != tb_cur) {
          tb_cur = tb;
          #pragma unroll
          for (int ks = 0; ks < 6; ++ks) {
            const uint32_t* p = (const uint32_t*)smem + tb * 1600 + l15 * 100 + ks * 16 + q * 4;
            bfr[ks] = *(const uint4*)p;
          }
        }
        f32x4 a = {0.f, 0.f, 0.f, 0.f};
        #pragma unroll
        for (int ks = 0; ks < 6; ++ks)
          a = __builtin_amdgcn_mfma_f32_16x16x32_f16(bc8(afr1[i * 6 + ks]), bc8(bfr[ks]), a, 0, 0, 0);
        acc[i] = a;
      }
    }
    __syncthreads();   // counts dead; LDS becomes feature space

    // ---- P5: primary features (D: col=l15=batch row, m=q*4+reg=u)
    {
      #pragma unroll
      for (int i = 0; i < 6; ++i) {
        int t  = w * 6 + i;
        int u0 = t * 16;
        int tb = tbs[i];
        int m0 = u0 + q * 4;
        f32x4 a = acc[i];
        if (tb == 0) {
          __half2* d = (__half2*)(smem + l15 * (FS_STRIDE * 2) + m0 * 2);
          d[0] = __floats2half2_rn(clampv(a[0]), clampv(a[1]));
          d[1] = __floats2half2_rn(clampv(a[2]), clampv(a[3]));
        } else if (tb == 1) {
          int s0 = m0 - 256;
          float4 tw = *(const float4*)(tempo_w + s0);
          float b0 = clampv(a[0] + wtr * tw.x);
          float b1 = clampv(a[1] + wtr * tw.y);
          float b2 = clampv(a[2] + wtr * tw.z);
          float b3 = clampv(a[3] + wtr * tw.w);
          __half2* dv = (__half2*)(smem + VA_BASE + l15 * (VA_STRIDE * 2) + s0 * 2);
          dv[0] = __floats2half2_rn(b0, b1);
          dv[1] = __floats2half2_rn(b2, b3);
          __half2* df = (__half2*)(smem + l15 * (FS_STRIDE * 2) + (256 + s0) * 2);
          df[0] = __floats2half2_rn(fabsf(b0), fabsf(b1));
          df[1] = __floats2half2_rn(fabsf(b2), fabsf(b3));
        } else if (tb == 2) {
          int s0 = m0 - 512;
          __half2* d = (__half2*)(smem + l15 * (FS_STRIDE * 2) + (512 + s0) * 2);
          d[0] = __floats2half2_rn(clampv(a[0]), clampv(a[1]));
          d[1] = __floats2half2_rn(clampv(a[2]), clampv(a[3]));
        } else {
          int s0 = m0 - 640;
          __half2* d = (__half2*)(smem + l15 * (FS_STRIDE * 2) + (640 + s0) * 2);
          d[0] = __floats2half2_rn(clampv(a[0]), clampv(a[1]));
          d[1] = __floats2half2_rn(clampv(a[2]), clampv(a[3]));
        }
      }
    }
    __syncthreads();

    // ---- P6: derived features: ab, |h|, |r|, h*r
    {
      uint32_t* fs32 = (uint32_t*)smem;
      uint32_t* va32 = (uint32_t*)(smem + VA_BASE);
      #pragma unroll
      for (int it = 0; it < 6; ++it) {
        int p = tid + 512 * it;
        if (p < 2048) {
          int row = p >> 7, kp = p & 127;
          union { uint32_t u; __half2 h; } a, b, r;
          a.u = fs32[row * 388 + kp];
          b.u = va32[row * 324 + kp];
          r.h = __hmul2(a.h, b.h);
          va32[row * 324 + 128 + kp] = r.u;
        } else {
          int pc = p - 2048;
          int row = pc >> 6, kp = pc & 63;
          union { uint32_t u; __half2 h; } h2, r2, pr;
          h2.u = fs32[row * 388 + 256 + kp];
          r2.u = fs32[row * 388 + 320 + kp];
          pr.h = __hmul2(h2.h, r2.h);
          fs32[row * 388 + 256 + kp] = h2.u & 0x7FFF7FFFu;
          fs32[row * 388 + 320 + kp] = r2.u & 0x7FFF7FFFu;
          va32[row * 324 + 256 + kp] = pr.u;
        }
      }
    }
    __syncthreads();

    // ---- P7: layer-2 split-K across all 8 waves
    float* exch = (float*)(smem + EX_BASE);
    {
      f32x4 a2acc = {0.f, 0.f, 0.f, 0.f};
      if (w < 4) {
        #pragma unroll
        for (int ks = 0; ks < 6; ++ks) {
          int k = w * 192 + ks * 32 + q * 8;
          uint4 bf = *(const uint4*)(smem + l15 * (FS_STRIDE * 2) + k * 2);
          a2acc = __builtin_amdgcn_mfma_f32_16x16x32_f16(bc8(a2[ks]), bc8(bf), a2acc, 0, 0, 0);
        }
      } else {
        #pragma unroll
        for (int ks = 0; ks < 5; ++ks) {
          int k = (w - 4) * 160 + ks * 32 + q * 8;
          uint4 bf = *(const uint4*)(smem + VA_BASE + l15 * (VA_STRIDE * 2) + k * 2);
          a2acc = __builtin_amdgcn_mfma_f32_16x16x32_f16(bc8(a2[ks]), bc8(bf), a2acc, 0, 0, 0);
        }
      }
      #pragma unroll
      for (int r = 0; r < 4; ++r)
        exch[w * 256 + (q * 4 + r) * 16 + l15] = a2acc[r];
    }
    __syncthreads();

    // ---- P8: combine partials, output.
    //      Threads 256-511 concurrently re-zero the count-grid bytes that do
    //      NOT overlap exch (0..45568 = int4 idx 0..2847, needs 12 rounds of
    //      256); the remaining 45568..49152 is zeroed by threads 16-239 after
    //      the internal barrier (exch then dead).
    float* prod = (float*)(smem + PROD_BASE);
    if (tid < 256) {
      float f = exch[tid] + exch[256 + tid] + exch[512 + tid] + exch[768 + tid] + bj;
      f = clampv(f);
      float v = exch[1024 + tid] + exch[1280 + tid] + exch[1536 + tid] + exch[1792 + tid];
      v = clampv(v);
      prod[tid] = v * w1j + f * v * w2j;
    } else if (g + 1 < GPB) {
      // zero int4 indices 0..2847 (bytes 0..45568), disjoint from exch/prod
      int4 z = make_int4(0, 0, 0, 0);
      int4* p = (int4*)smem;
      int t2 = tid - 256;                  // 0..255
      #pragma unroll
      for (int i = 0; i < 12; ++i) {       // 12 * 256 = 3072 >= 2848 (was 11: BUG)
        int idx = t2 + 256 * i;
        if (idx < 2848) p[idx] = z;
      }
    }
    __syncthreads();
    if (tid < 16) {
      float s = 0.f;
      #pragma unroll
      for (int j = 0; j < 16; ++j) s += prod[j * 16 + tid];
      out[r0 + tid] = s;
    } else if (tid < 240 && g + 1 < GPB) {
      // zero int4 indices 2848..3071 (bytes 45568..49152) -- exch is dead now
      int4 z = make_int4(0, 0, 0, 0);
      ((int4*)smem)[2848 + (tid - 16)] = z;
    }
    __syncthreads();
    wtr = nwt;
  }
}

extern "C" void kernel_launch(void* const* d_in, const int* in_sizes, int n_in,
                              void* d_out, int out_size, void* d_ws, size_t ws_size,
                              hipStream_t stream) {
  const int*   pst_idx     = (const int*)  d_in[0];
  const float* color_sign  = (const float*)d_in[1];
  const float* sob_sign    = (const float*)d_in[2];
  const float* wtm         = (const float*)d_in[3];
  const float* emb_fs      = (const float*)d_in[4];
  const float* emb_va      = (const float*)d_in[5];
  const float* emb_ha      = (const float*)d_in[6];
  const float* emb_ra      = (const float*)d_in[7];
  const float* tempo_w     = (const float*)d_in[8];
  const float* fs_b        = (const float*)d_in[10];
  const float* fs_w        = (const float*)d_in[9];
  const float* absva_w     = (const float*)d_in[11];
  const float* absha_w     = (const float*)d_in[12];
  const float* absra_w     = (const float*)d_in[13];
  const float* va_w        = (const float*)d_in[14];
  const float* fsxva_w     = (const float*)d_in[15];
  const float* haxra_w     = (const float*)d_in[16];
  const float* out_va_w    = (const float*)d_in[17];
  const float* out_fsxva_w = (const float*)d_in[18];
  float* out = (float*)d_out;
  f16* ws = (f16*)d_ws;

  prepack<<<24 + 88, 256, 0, stream>>>(emb_fs, emb_va, emb_ha, emb_ra,
                                       fs_w, absva_w, absha_w, absra_w,
                                       va_w, fsxva_w, haxra_w, ws);
  rengar_main<<<NBLK, TPB, 0, stream>>>(pst_idx, color_sign, sob_sign, wtm,
                                        tempo_w, fs_b, out_va_w, out_fsxva_w,
                                        ws, out);
}